// Round 1
// baseline (44.048 us; speedup 1.0000x reference)
//
#include <hip/hip_runtime.h>

// GraphConvolution_relative: out = relu(einsum('sn,sd->nd', diag, w))
// where diag[s,i] = sum_{e: rows[s,e]==i} vals[s,e] * |x[rows,cols] + x[cols,rows]|
//
// Phase 1: memset diag (2*8192 fp32 in d_ws)
// Phase 2: edge scatter — 2 gathers from x per edge + atomicAdd into diag
// Phase 3: epilogue — out[n,d] = relu(diag[0][n]*w[0][d] + diag[1][n]*w[1][d])

#define N_NODES 8192
#define S_SUP   2
#define E_EDGES 262144   // 2^18
#define D_OUT   128

__global__ void gc_edge_kernel(const float* __restrict__ x,
                               const int*   __restrict__ rows,
                               const int*   __restrict__ cols,
                               const float* __restrict__ vals,
                               float*       __restrict__ diag) {
    int idx = blockIdx.x * blockDim.x + threadIdx.x;
    if (idx >= S_SUP * E_EDGES) return;
    int s = idx >> 18;                 // idx / E_EDGES
    int r = rows[idx];
    int c = cols[idx];
    float v = vals[idx];
    float a = x[(size_t)r * N_NODES + c];
    float b = x[(size_t)c * N_NODES + r];
    float t = fabsf(a + b) * v;
    atomicAdd(&diag[s * N_NODES + r], t);
}

__global__ void gc_out_kernel(const float* __restrict__ diag,
                              const float* __restrict__ w,
                              float*       __restrict__ out) {
    // one thread per 4 outputs along D (float4-vectorized)
    int idx = blockIdx.x * blockDim.x + threadIdx.x;   // over N*D/4
    int d4 = idx & (D_OUT / 4 - 1);                    // 0..31
    int n  = idx >> 5;
    if (n >= N_NODES) return;
    float d0 = diag[n];
    float d1 = diag[N_NODES + n];
    const float4 w0 = ((const float4*)w)[d4];               // w[0][d..d+3]
    const float4 w1 = ((const float4*)w)[D_OUT / 4 + d4];   // w[1][d..d+3]
    float4 o;
    o.x = fmaxf(fmaf(d0, w0.x, d1 * w1.x), 0.0f);
    o.y = fmaxf(fmaf(d0, w0.y, d1 * w1.y), 0.0f);
    o.z = fmaxf(fmaf(d0, w0.z, d1 * w1.z), 0.0f);
    o.w = fmaxf(fmaf(d0, w0.w, d1 * w1.w), 0.0f);
    ((float4*)out)[idx] = o;
}

extern "C" void kernel_launch(void* const* d_in, const int* in_sizes, int n_in,
                              void* d_out, int out_size, void* d_ws, size_t ws_size,
                              hipStream_t stream) {
    const float* x    = (const float*)d_in[0];
    const int*   rows = (const int*)  d_in[1];
    const int*   cols = (const int*)  d_in[2];
    const float* vals = (const float*)d_in[3];
    const float* w    = (const float*)d_in[4];
    float* out  = (float*)d_out;
    float* diag = (float*)d_ws;   // S_SUP * N_NODES floats = 64 KB

    hipMemsetAsync(diag, 0, (size_t)S_SUP * N_NODES * sizeof(float), stream);

    {
        int total = S_SUP * E_EDGES;
        int block = 256;
        int grid  = (total + block - 1) / block;
        gc_edge_kernel<<<grid, block, 0, stream>>>(x, rows, cols, vals, diag);
    }
    {
        int total = N_NODES * D_OUT / 4;
        int block = 256;
        int grid  = (total + block - 1) / block;
        gc_out_kernel<<<grid, block, 0, stream>>>(diag, w, out);
    }
}